// Round 1
// baseline (388.027 us; speedup 1.0000x reference)
//
#include <hip/hip_runtime.h>
#include <hip/hip_bf16.h>
#include <stdint.h>

// ---------------------------------------------------------------------------
// CapsuleLayerSemantic: LN -> per-adapter (W1,relu,W2) -> capsule squash over A
// B=16 S=2048 NX=1024 A=20 H=50 O=3.  M = B*S = 32768 tokens.
// Strategy: fp16 MFMA GEMM (M=32768,K=1024,N=20*64 padded) + fused epilogue.
// ---------------------------------------------------------------------------

typedef _Float16 h8 __attribute__((ext_vector_type(8)));
typedef float f4 __attribute__((ext_vector_type(4)));
typedef __attribute__((address_space(1))) void gvoid;
typedef __attribute__((address_space(3))) void lvoid;

__device__ __forceinline__ void cp16(const void* g, void* l) {
  // async global->LDS, 16B per lane; LDS dest = wave-uniform base + lane*16
  __builtin_amdgcn_global_load_lds((gvoid*)g, (lvoid*)l, 16, 0, 0);
}

// ---------------- kernel 1: layernorm + fp16 cast ---------------------------
__global__ __launch_bounds__(256) void ln_kernel(const float* __restrict__ x,
                                                 _Float16* __restrict__ xn) {
  const int tok = blockIdx.x, t = threadIdx.x;
  const float4* xr = (const float4*)(x + (size_t)tok * 1024);
  float4 v = xr[t];
  float s1 = v.x + v.y + v.z + v.w;
  float s2 = v.x * v.x + v.y * v.y + v.z * v.z + v.w * v.w;
#pragma unroll
  for (int o = 32; o > 0; o >>= 1) {
    s1 += __shfl_down(s1, o);
    s2 += __shfl_down(s2, o);
  }
  __shared__ float r1[4], r2[4];
  const int w = t >> 6, l = t & 63;
  if (l == 0) { r1[w] = s1; r2[w] = s2; }
  __syncthreads();
  s1 = r1[0] + r1[1] + r1[2] + r1[3];
  s2 = r2[0] + r2[1] + r2[2] + r2[3];
  const float mu = s1 * 0.0009765625f;
  const float var = s2 * 0.0009765625f - mu * mu;
  const float inv = rsqrtf(var + 1e-5f);
  union { _Float16 h[4]; uint2 u; } p;
  p.h[0] = (_Float16)((v.x - mu) * inv);
  p.h[1] = (_Float16)((v.y - mu) * inv);
  p.h[2] = (_Float16)((v.z - mu) * inv);
  p.h[3] = (_Float16)((v.w - mu) * inv);
  *(uint2*)(xn + (size_t)tok * 1024 + t * 4) = p.u;
}

// ---------------- kernel 2: fold ln_g into W1, transpose to [n][k] fp16 -----
// wB[n][k], n = a*64+h (h>=50 zero-padded), k-contiguous rows.
__global__ __launch_bounds__(256) void prep_w1(const float* __restrict__ ln_g,
                                               const float* __restrict__ W1,
                                               _Float16* __restrict__ wB) {
  const int idx = blockIdx.x * 256 + threadIdx.x;  // 0 .. 1280*1024-1
  const int n = idx >> 10, k = idx & 1023;
  const int a = n >> 6, h = n & 63;
  float v = 0.f;
  if (h < 50) v = ln_g[a * 1024 + k] * W1[(size_t)(a * 1024 + k) * 50 + h];
  wB[idx] = (_Float16)v;
}

// ---------------- kernel 3: off[a][h] = ln_b . W1 + b1  (padded to 64) ------
__global__ __launch_bounds__(256) void prep_off(const float* __restrict__ ln_b,
                                                const float* __restrict__ W1,
                                                const float* __restrict__ b1,
                                                float* __restrict__ offw) {
  const int a = blockIdx.x, t = threadIdx.x;
  const int h = t & 63, kc = t >> 6;  // kc = 0..3
  float p = 0.f;
  if (h < 50) {
    for (int k = kc * 256; k < kc * 256 + 256; ++k)
      p += ln_b[a * 1024 + k] * W1[(size_t)(a * 1024 + k) * 50 + h];
  }
  __shared__ float red[256];
  red[t] = p;
  __syncthreads();
  if (kc == 0) {
    float s = red[h] + red[64 + h] + red[128 + h] + red[192 + h];
    offw[a * 64 + h] = s + ((h < 50) ? b1[a * 50 + h] : 0.f);
  }
}

// ---------------- kernel 4: main GEMM + epilogue ----------------------------
// grid (10, 256): blockIdx.x = n-block (2 adapters), blockIdx.y = m-block.
// 128x128 tile, BK=64, mfma_f32_16x16x32_f16, 4 waves in 2x2.
// LDS tile layout (A and B identical): elem (r,k) at byte
//   r*128 + (((k>>3) ^ (r&7))*16) + (k&7)*2   (XOR swizzle kills bank conflicts
//   while keeping global_load_lds's lane-contiguous LDS destination legal:
//   the swizzle is applied on the global-gather side.)
__global__ __launch_bounds__(256, 2) void gemm_kernel(
    const _Float16* __restrict__ xn, const _Float16* __restrict__ wB,
    const float* __restrict__ offw, const float* __restrict__ W2,
    const float* __restrict__ b2, float* __restrict__ out) {
  __shared__ __align__(16) char smem[69320];
  // [0,16384)      sA      (later reused: hm = float[128][133] = 68096 B)
  // [16384,32768)  sB
  // [68096,69320)  w2s: 300 floats (W2 pair) + 6 floats (b2 pair)
  const int nb = blockIdx.x, mb = blockIdx.y;
  const int t = threadIdx.x;
  const int w = t >> 6, l = t & 63;

  float* w2s = (float*)(smem + 68096);
  for (int i = t; i < 300; i += 256) w2s[i] = W2[nb * 300 + i];
  if (t < 6) w2s[300 + t] = b2[nb * 6 + t];

  // staging addresses: chunk = 8 rows (1 KB LDS); lane l -> row chunk*8+(l>>3),
  // physical 16B slot l&7, holding logical k-slot (l&7)^(l>>3).
  const int lr = l >> 3;
  const int ksl = (l & 7) ^ lr;
  const _Float16* gA = xn + (size_t)(mb * 128 + lr) * 1024 + ksl * 8;
  const _Float16* gB = wB + (size_t)(nb * 128 + lr) * 1024 + ksl * 8;

  // fragment-read addressing
  const int rowA = ((w >> 1) * 64) + (l & 15);
  const int rowB = ((w & 1) * 64) + (l & 15);
  const int kq = l >> 4;
  const int xa = rowA & 7, xb = rowB & 7;
  const char* pA = smem + rowA * 128;
  const char* pB = smem + 16384 + rowB * 128;

  f4 acc[4][4];
  {
    f4 z = {0.f, 0.f, 0.f, 0.f};
#pragma unroll
    for (int mt = 0; mt < 4; ++mt)
#pragma unroll
      for (int nt = 0; nt < 4; ++nt) acc[mt][nt] = z;
  }

  for (int kt = 0; kt < 16; ++kt) {
#pragma unroll
    for (int i = 0; i < 4; ++i) {
      const int chunk = w * 4 + i;
      cp16(gA + (size_t)chunk * 8192 + kt * 64, smem + chunk * 1024);
      cp16(gB + (size_t)chunk * 8192 + kt * 64, smem + 16384 + chunk * 1024);
    }
    __syncthreads();  // drains global_load_lds (vmcnt0) + joins
#pragma unroll
    for (int ks = 0; ks < 2; ++ks) {
      h8 af[4], bf[4];
      const int sl = ks * 4 + kq;
#pragma unroll
      for (int mt = 0; mt < 4; ++mt)
        af[mt] = *(const h8*)(pA + mt * 2048 + ((sl ^ xa) << 4));
#pragma unroll
      for (int nt = 0; nt < 4; ++nt)
        bf[nt] = *(const h8*)(pB + nt * 2048 + ((sl ^ xb) << 4));
#pragma unroll
      for (int mt = 0; mt < 4; ++mt)
#pragma unroll
        for (int nt = 0; nt < 4; ++nt)
          acc[mt][nt] = __builtin_amdgcn_mfma_f32_16x16x32_f16(
              af[mt], bf[nt], acc[mt][nt], 0, 0, 0);
    }
    __syncthreads();  // protect LDS before next stage overwrites
  }

  // ---- epilogue: h = relu(acc + off) -> LDS, then o = h . W2 (+b2) ----
  float offv[4];
#pragma unroll
  for (int nt = 0; nt < 4; ++nt) offv[nt] = offw[nb * 128 + rowB + nt * 16];

  float* hm = (float*)smem;  // [128][133], stride 133 breaks bank conflicts
  const int mrow = (w >> 1) * 64 + (l >> 4) * 4;  // C/D: row=(lane>>4)*4+reg
  const int ncol = (w & 1) * 64 + (l & 15);       //      col=lane&15
#pragma unroll
  for (int mt = 0; mt < 4; ++mt)
#pragma unroll
    for (int nt = 0; nt < 4; ++nt)
#pragma unroll
      for (int r = 0; r < 4; ++r) {
        float v = acc[mt][nt][r] + offv[nt];
        hm[(mrow + mt * 16 + r) * 133 + (ncol + nt * 16)] = fmaxf(v, 0.f);
      }
  __syncthreads();

  const int m = t >> 1, pr = t & 1;
  const float* hrow = hm + m * 133 + pr * 64;
  const float* wrow = w2s + pr * 150;
  float o0 = w2s[300 + pr * 3 + 0];
  float o1 = w2s[300 + pr * 3 + 1];
  float o2 = w2s[300 + pr * 3 + 2];
#pragma unroll 10
  for (int h = 0; h < 50; ++h) {
    const float hv = hrow[h];
    o0 += hv * wrow[h * 3 + 0];
    o1 += hv * wrow[h * 3 + 1];
    o2 += hv * wrow[h * 3 + 2];
  }
  const int tok = mb * 128 + m;
  const int b = tok >> 11, s = tok & 2047;
  const int ag = nb * 2 + pr;
  float* op = out + ((size_t)(b * 20 + ag) * 2048 + (size_t)s) * 3;
  op[0] = o0;
  op[1] = o1;
  op[2] = o2;
}

// ---------------- kernel 5: capsule squash over A, in place -----------------
__global__ __launch_bounds__(256) void squash_kernel(float* __restrict__ out) {
  const int idx = blockIdx.x * 256 + threadIdx.x;  // 0 .. 16*6144-1
  const int b = idx / 6144;
  const int rem = idx - b * 6144;
  float v[20];
  float sq = 0.f;
#pragma unroll
  for (int a = 0; a < 20; ++a) {
    v[a] = out[((size_t)(b * 20 + a)) * 6144 + rem];
    sq += v[a] * v[a];
  }
  const float f = sqrtf(sq) / (1.f + sq);  // == (sq/(1+sq)) * rsqrt(sq), safe at 0
#pragma unroll
  for (int a = 0; a < 20; ++a)
    out[((size_t)(b * 20 + a)) * 6144 + rem] = v[a] * f;
}

// ---------------------------------------------------------------------------
extern "C" void kernel_launch(void* const* d_in, const int* in_sizes, int n_in,
                              void* d_out, int out_size, void* d_ws,
                              size_t ws_size, hipStream_t stream) {
  const float* x    = (const float*)d_in[0];  // [16,2048,1024]
  const float* ln_g = (const float*)d_in[1];  // [20,1024]
  const float* ln_b = (const float*)d_in[2];  // [20,1024]
  const float* W1   = (const float*)d_in[3];  // [20,1024,50]
  const float* b1   = (const float*)d_in[4];  // [20,50]
  const float* W2   = (const float*)d_in[5];  // [20,50,3]
  const float* b2   = (const float*)d_in[6];  // [20,3]
  float* out = (float*)d_out;                 // [16,20,6144]

  char* ws = (char*)d_ws;
  float* offw   = (float*)ws;                        // 1280 f32 (5120 B)
  _Float16* wB  = (_Float16*)(ws + 8192);            // 1280*1024 fp16 (2.62 MB)
  _Float16* xnw = (_Float16*)(ws + 8192 + 2621440);  // 32768*1024 fp16 (67.1 MB)

  ln_kernel<<<32768, 256, 0, stream>>>(x, xnw);
  prep_w1<<<5120, 256, 0, stream>>>(ln_g, W1, wB);
  prep_off<<<20, 256, 0, stream>>>(ln_b, W1, b1, offw);
  gemm_kernel<<<dim3(10, 256), 256, 0, stream>>>(xnw, wB, offw, W2, b2, out);
  squash_kernel<<<384, 256, 0, stream>>>(out);
}

// Round 3
// 317.604 us; speedup vs baseline: 1.2217x; 1.2217x over previous
//
#include <hip/hip_runtime.h>
#include <hip/hip_bf16.h>
#include <stdint.h>

// ---------------------------------------------------------------------------
// CapsuleLayerSemantic: LN -> per-adapter (W1,relu,W2) -> capsule squash over A
// B=16 S=2048 NX=1024 A=20 H=50 O=3.  M = B*S = 32768 tokens.
// fp16 MFMA GEMM (M=32768,K=1024,N=20*64 padded) + fused epilogue.
// R3: fix prep_w k-coverage bug (R2 wrote only k%64<32 of wB -> poison).
//     Keeps R2's 2-pass epilogue (LDS 35.3KB -> 4 blocks/CU) to test occupancy.
// ---------------------------------------------------------------------------

typedef _Float16 h8 __attribute__((ext_vector_type(8)));
typedef float f4 __attribute__((ext_vector_type(4)));
typedef __attribute__((address_space(1))) void gvoid;
typedef __attribute__((address_space(3))) void lvoid;

__device__ __forceinline__ void cp16(const void* g, void* l) {
  __builtin_amdgcn_global_load_lds((gvoid*)g, (lvoid*)l, 16, 0, 0);
}

// ---------------- kernel 1: layernorm + fp16 cast (one wave per token) ------
__global__ __launch_bounds__(256) void ln_kernel(const float* __restrict__ x,
                                                 _Float16* __restrict__ xn) {
  const int t = threadIdx.x, w = t >> 6, l = t & 63;
  const int tok = blockIdx.x * 4 + w;
  const float4* xr = (const float4*)(x + (size_t)tok * 1024);
  float4 v0 = xr[l * 2], v1 = xr[l * 2 + 1];
  float4 v2 = xr[128 + l * 2], v3 = xr[128 + l * 2 + 1];
  float s1 = (v0.x + v0.y + v0.z + v0.w) + (v1.x + v1.y + v1.z + v1.w) +
             (v2.x + v2.y + v2.z + v2.w) + (v3.x + v3.y + v3.z + v3.w);
  float s2 = v0.x * v0.x + v0.y * v0.y + v0.z * v0.z + v0.w * v0.w;
  s2 += v1.x * v1.x + v1.y * v1.y + v1.z * v1.z + v1.w * v1.w;
  s2 += v2.x * v2.x + v2.y * v2.y + v2.z * v2.z + v2.w * v2.w;
  s2 += v3.x * v3.x + v3.y * v3.y + v3.z * v3.z + v3.w * v3.w;
#pragma unroll
  for (int m = 32; m > 0; m >>= 1) {
    s1 += __shfl_xor(s1, m);
    s2 += __shfl_xor(s2, m);
  }
  const float mu = s1 * 0.0009765625f;
  const float var = s2 * 0.0009765625f - mu * mu;
  const float inv = rsqrtf(var + 1e-5f);
  union { _Float16 h[8]; uint4 u; } p;
  _Float16* xw = xn + (size_t)tok * 1024 + l * 8;
  p.h[0] = (_Float16)((v0.x - mu) * inv); p.h[1] = (_Float16)((v0.y - mu) * inv);
  p.h[2] = (_Float16)((v0.z - mu) * inv); p.h[3] = (_Float16)((v0.w - mu) * inv);
  p.h[4] = (_Float16)((v1.x - mu) * inv); p.h[5] = (_Float16)((v1.y - mu) * inv);
  p.h[6] = (_Float16)((v1.z - mu) * inv); p.h[7] = (_Float16)((v1.w - mu) * inv);
  *(uint4*)xw = p.u;
  p.h[0] = (_Float16)((v2.x - mu) * inv); p.h[1] = (_Float16)((v2.y - mu) * inv);
  p.h[2] = (_Float16)((v2.z - mu) * inv); p.h[3] = (_Float16)((v2.w - mu) * inv);
  p.h[4] = (_Float16)((v3.x - mu) * inv); p.h[5] = (_Float16)((v3.y - mu) * inv);
  p.h[6] = (_Float16)((v3.z - mu) * inv); p.h[7] = (_Float16)((v3.w - mu) * inv);
  *(uint4*)(xw + 512) = p.u;
}

// ---------------- kernel 2: prep — W1 transpose*ln_g -> fp16, off partials --
// grid (20,16): a, k-chunk of 64. Coalesced W1 tile read -> LDS, 16B wB
// stores. Each thread covers k = q*16 .. q*16+15 (q = t>>6) via two 8-wide
// stores — full 64-k coverage (R2 bug: only 0..31).
__global__ __launch_bounds__(256) void prep_w(const float* __restrict__ ln_g,
                                              const float* __restrict__ ln_b,
                                              const float* __restrict__ W1,
                                              _Float16* __restrict__ wB,
                                              float* __restrict__ offacc) {
  const int a = blockIdx.x, k0 = blockIdx.y * 64, t = threadIdx.x;
  __shared__ float tw[3200];  // W1[a][k0..k0+64][0..50] flat
  __shared__ float gg[64], bb[64];
  const float* src = W1 + (size_t)(a * 1024 + k0) * 50;
  for (int i = t; i < 3200; i += 256) tw[i] = src[i];
  if (t < 64) gg[t] = ln_g[a * 1024 + k0 + t];
  else if (t < 128) bb[t - 64] = ln_b[a * 1024 + k0 + (t - 64)];
  __syncthreads();
  const int h = t & 63, q = t >> 6;  // q in 0..3, each handles 16 k's
  float po = 0.f;
#pragma unroll
  for (int half = 0; half < 2; ++half) {
    union { _Float16 hh[8]; uint4 u; } pk;
#pragma unroll
    for (int j = 0; j < 8; ++j) {
      const int k = q * 16 + half * 8 + j;
      float wv = (h < 50) ? tw[k * 50 + h] : 0.f;
      pk.hh[j] = (_Float16)(gg[k] * wv);
      po += bb[k] * wv;
    }
    *(uint4*)(wB + (size_t)(a * 64 + h) * 1024 + k0 + q * 16 + half * 8) =
        pk.u;
  }
  if (h < 50 && po != 0.f) atomicAdd(&offacc[a * 64 + h], po);
}

// ---------------- kernel 3: main GEMM + fused epilogue ----------------------
// grid (10, 256): blockIdx.x = n-block (2 adapters), blockIdx.y = m-block.
// 128x128 tile, BK=64, mfma_f32_16x16x32_f16, 4 waves 2x2. XOR-swizzled LDS
// (swizzle applied on the global-gather side so global_load_lds stays legal).
// Epilogue in two 64-row passes so LDS stays at 35.3KB -> 4 blocks/CU.
__global__ __launch_bounds__(256, 4) void gemm_kernel(
    const _Float16* __restrict__ xn, const _Float16* __restrict__ wB,
    const float* __restrict__ offacc, const float* __restrict__ b1,
    const float* __restrict__ W2, const float* __restrict__ b2,
    float* __restrict__ out) {
  __shared__ __align__(16) char smem[35280];
  // [0,16384) sA | [16384,32768) sB | epilogue reuse: hm = float[64][133]=34048
  // [34048, 34048+1224) w2s: 300 f32 W2 + 6 f32 b2
  const int nb = blockIdx.x, mb = blockIdx.y;
  const int t = threadIdx.x, w = t >> 6, l = t & 63;

  float* w2s = (float*)(smem + 34048);
  for (int i = t; i < 300; i += 256) w2s[i] = W2[nb * 300 + i];
  if (t < 6) w2s[300 + t] = b2[nb * 6 + t];

  // staging: chunk = 8 rows (1KB); lane -> row chunk*8+(l>>3), phys slot l&7
  // holding logical k-slot (l&7)^(l>>3).
  const int lr = l >> 3;
  const int ksl = (l & 7) ^ lr;
  const _Float16* gA = xn + (size_t)(mb * 128 + lr) * 1024 + ksl * 8;
  const _Float16* gB = wB + (size_t)(nb * 128 + lr) * 1024 + ksl * 8;

  const int rowA = ((w >> 1) * 64) + (l & 15);
  const int rowB = ((w & 1) * 64) + (l & 15);
  const int kq = l >> 4;
  const int xa = rowA & 7, xb = rowB & 7;
  const char* pA = smem + rowA * 128;
  const char* pB = smem + 16384 + rowB * 128;

  f4 acc[4][4];
  {
    f4 z = {0.f, 0.f, 0.f, 0.f};
#pragma unroll
    for (int mt = 0; mt < 4; ++mt)
#pragma unroll
      for (int nt = 0; nt < 4; ++nt) acc[mt][nt] = z;
  }

  for (int kt = 0; kt < 16; ++kt) {
#pragma unroll
    for (int i = 0; i < 4; ++i) {
      const int chunk = w * 4 + i;
      cp16(gA + (size_t)chunk * 8192 + kt * 64, smem + chunk * 1024);
      cp16(gB + (size_t)chunk * 8192 + kt * 64, smem + 16384 + chunk * 1024);
    }
    __syncthreads();
#pragma unroll
    for (int ks = 0; ks < 2; ++ks) {
      h8 af[4], bf[4];
      const int sl = ks * 4 + kq;
#pragma unroll
      for (int mt = 0; mt < 4; ++mt)
        af[mt] = *(const h8*)(pA + mt * 2048 + ((sl ^ xa) << 4));
#pragma unroll
      for (int nt = 0; nt < 4; ++nt)
        bf[nt] = *(const h8*)(pB + nt * 2048 + ((sl ^ xb) << 4));
#pragma unroll
      for (int mt = 0; mt < 4; ++mt)
#pragma unroll
        for (int nt = 0; nt < 4; ++nt)
          acc[mt][nt] = __builtin_amdgcn_mfma_f32_16x16x32_f16(
              af[mt], bf[nt], acc[mt][nt], 0, 0, 0);
    }
    __syncthreads();
  }

  // off_total[nt] = offacc[n] + b1[a][h] (h<50), n = nb*128 + rowB + nt*16
  float offt[4];
#pragma unroll
  for (int nt = 0; nt < 4; ++nt) {
    const int nc = rowB + nt * 16;            // 0..127
    const int hh = nc & 63;
    float bv = (hh < 50) ? b1[(nb * 2 + (nc >> 6)) * 50 + hh] : 0.f;
    offt[nt] = offacc[nb * 128 + nc] + bv;
  }

  float* hm = (float*)smem;  // [64][133]
  const int mrl = (l >> 4) * 4;               // C/D row base within 64-half
  const int ncol = (w & 1) * 64 + (l & 15);
#pragma unroll
  for (int p = 0; p < 2; ++p) {
    if (p) __syncthreads();
    if ((w >> 1) == p) {
#pragma unroll
      for (int mt = 0; mt < 4; ++mt)
#pragma unroll
        for (int nt = 0; nt < 4; ++nt)
#pragma unroll
          for (int r = 0; r < 4; ++r)
            hm[(mrl + mt * 16 + r) * 133 + (ncol + nt * 16)] =
                fmaxf(acc[mt][nt][r] + offt[nt], 0.f);
    }
    __syncthreads();
    if (t < 128) {
      const int ml = t >> 1, pr = t & 1;
      const float* hrow = hm + ml * 133 + pr * 64;
      const float* wrow = w2s + pr * 150;
      float o0 = w2s[300 + pr * 3 + 0];
      float o1 = w2s[300 + pr * 3 + 1];
      float o2 = w2s[300 + pr * 3 + 2];
#pragma unroll 10
      for (int h = 0; h < 50; ++h) {
        const float hv = hrow[h];
        o0 += hv * wrow[h * 3 + 0];
        o1 += hv * wrow[h * 3 + 1];
        o2 += hv * wrow[h * 3 + 2];
      }
      const int tok = mb * 128 + p * 64 + ml;
      const int b = tok >> 11, s = tok & 2047;
      const int ag = nb * 2 + pr;
      float* op = out + ((size_t)(b * 20 + ag) * 2048 + (size_t)s) * 3;
      op[0] = o0; op[1] = o1; op[2] = o2;
    }
  }
}

// ---------------- kernel 4: capsule squash over A, in place -----------------
__global__ __launch_bounds__(256) void squash_kernel(float* __restrict__ out) {
  const int idx = blockIdx.x * 256 + threadIdx.x;  // 0 .. 16*6144-1
  const int b = idx / 6144;
  const int rem = idx - b * 6144;
  float v[20];
  float sq = 0.f;
#pragma unroll
  for (int a = 0; a < 20; ++a) {
    v[a] = out[((size_t)(b * 20 + a)) * 6144 + rem];
    sq += v[a] * v[a];
  }
  const float f = sqrtf(sq) / (1.f + sq);  // (sq/(1+sq))*rsqrt(sq), safe at 0
#pragma unroll
  for (int a = 0; a < 20; ++a)
    out[((size_t)(b * 20 + a)) * 6144 + rem] = v[a] * f;
}

// ---------------------------------------------------------------------------
extern "C" void kernel_launch(void* const* d_in, const int* in_sizes, int n_in,
                              void* d_out, int out_size, void* d_ws,
                              size_t ws_size, hipStream_t stream) {
  const float* x    = (const float*)d_in[0];  // [16,2048,1024]
  const float* ln_g = (const float*)d_in[1];  // [20,1024]
  const float* ln_b = (const float*)d_in[2];  // [20,1024]
  const float* W1   = (const float*)d_in[3];  // [20,1024,50]
  const float* b1   = (const float*)d_in[4];  // [20,50]
  const float* W2   = (const float*)d_in[5];  // [20,50,3]
  const float* b2   = (const float*)d_in[6];  // [20,3]
  float* out = (float*)d_out;                 // [16,20,6144]

  char* ws = (char*)d_ws;
  float* offacc = (float*)ws;                        // 1280 f32
  _Float16* wB  = (_Float16*)(ws + 8192);            // 1280*1024 fp16 (2.62MB)
  _Float16* xnw = (_Float16*)(ws + 8192 + 2621440);  // 32768*1024 fp16 (67.1MB)

  hipMemsetAsync(offacc, 0, 1280 * sizeof(float), stream);
  prep_w<<<dim3(20, 16), 256, 0, stream>>>(ln_g, ln_b, W1, wB, offacc);
  ln_kernel<<<8192, 256, 0, stream>>>(x, xnw);
  gemm_kernel<<<dim3(10, 256), 256, 0, stream>>>(xnw, wB, offacc, b1, W2, b2, out);
  squash_kernel<<<384, 256, 0, stream>>>(out);
}